// Round 1
// baseline (435.526 us; speedup 1.0000x reference)
//
#include <hip/hip_runtime.h>

#define NB 8
#define NN 20000
#define FI 128
#define FO 128
#define NE 320000
#define ROWS (NB * NN)        // 160000 flattened (b,n) rows
#define LRALPHA 0.2f

typedef short bf16x8 __attribute__((ext_vector_type(8)));
typedef float f32x4 __attribute__((ext_vector_type(4)));

static __device__ __forceinline__ float b2f(unsigned short u) {
  return __uint_as_float(((unsigned int)u) << 16);
}
static __device__ __forceinline__ unsigned short f2b(float f) {
  unsigned int u = __float_as_uint(f);
  return (unsigned short)((u + 0x7FFFu + ((u >> 16) & 1u)) >> 16);  // RNE
}

// ---------------- GEMM: h[row][o] = sum_k x[row][k]*W[k][o], h stored bf16 ---
#define LDW 136  // padded LDS stride (bf16 elems): 272B rows -> 2-way bank alias only (free)

__global__ __launch_bounds__(256) void gemm_kernel(
    const float* __restrict__ x, const float* __restrict__ W,
    unsigned short* __restrict__ hb) {
  __shared__ __align__(16) unsigned short Wt[128 * LDW];  // Wt[n][k]  (transposed W)
  __shared__ __align__(16) unsigned short Xs[64 * LDW];   // Xs[r][k]
  const int tid = threadIdx.x;

  // stage W fp32 -> bf16, transposed
  for (int i = 0; i < 64; ++i) {
    int idx = tid + i * 256;        // 0..16383, coalesced read
    int k = idx >> 7, n = idx & 127;
    Wt[n * LDW + k] = f2b(W[idx]);
  }
  // stage 64 x-rows fp32 -> bf16
  const size_t row0 = (size_t)blockIdx.x * 64;
  const float4* xv = (const float4*)(x + row0 * 128);
  for (int i = 0; i < 8; ++i) {
    int c = tid + i * 256;          // float4 chunk 0..2047
    float4 v = xv[c];
    int r = c >> 5;                 // 32 float4 per 128-wide row
    int k = (c & 31) * 4;
    ushort4 o;
    o.x = f2b(v.x); o.y = f2b(v.y); o.z = f2b(v.z); o.w = f2b(v.w);
    *(ushort4*)&Xs[r * LDW + k] = o;
  }
  __syncthreads();

  const int wv = tid >> 6;          // wave 0..3 -> rows [wv*16, wv*16+16)
  const int lane = tid & 63;
  const int m = lane & 15;
  const int quad = lane >> 4;
  f32x4 acc[8] = {};
#pragma unroll
  for (int k0 = 0; k0 < 128; k0 += 32) {
    bf16x8 af = *(const bf16x8*)&Xs[(wv * 16 + m) * LDW + k0 + quad * 8];
#pragma unroll
    for (int c = 0; c < 8; ++c) {
      bf16x8 bf = *(const bf16x8*)&Wt[(c * 16 + m) * LDW + k0 + quad * 8];
      acc[c] = __builtin_amdgcn_mfma_f32_16x16x32_bf16(af, bf, acc[c], 0, 0, 0);
    }
  }
  // C/D layout: col = lane&15, row = quad*4 + r  (m89-verified)
  unsigned short* hp = hb + (row0 + (size_t)wv * 16) * 128;
#pragma unroll
  for (int c = 0; c < 8; ++c)
#pragma unroll
    for (int r = 0; r < 4; ++r)
      hp[(quad * 4 + r) * 128 + c * 16 + m] = f2b(acc[c][r]);
}

// ---------------- g1/g2 = h @ a1, h @ a2 per row ----------------------------
__global__ __launch_bounds__(256) void g_kernel(
    const unsigned short* __restrict__ hb, const float* __restrict__ a,
    float* __restrict__ g1, float* __restrict__ g2) {
  int row = blockIdx.x * 4 + (threadIdx.x >> 6);
  int lane = threadIdx.x & 63;
  const unsigned short* hr = hb + (size_t)row * 128;
  ushort2 hv = *(const ushort2*)&hr[2 * lane];
  float h0 = b2f(hv.x), h1 = b2f(hv.y);
  float p1 = h0 * a[2 * lane] + h1 * a[2 * lane + 1];
  float p2 = h0 * a[128 + 2 * lane] + h1 * a[128 + 2 * lane + 1];
#pragma unroll
  for (int off = 32; off >= 1; off >>= 1) {
    p1 += __shfl_xor(p1, off, 64);
    p2 += __shfl_xor(p2, off, 64);
  }
  if (lane == 0) { g1[row] = p1; g2[row] = p2; }
}

// ---------------- CSR build: histogram -> scan -> scatter -------------------
__global__ __launch_bounds__(256) void hist_kernel(const int* __restrict__ src,
                                                   int* __restrict__ counts) {
  int e = blockIdx.x * 256 + threadIdx.x;
  if (e < NE) atomicAdd(&counts[src[e]], 1);
}

__global__ __launch_bounds__(1024) void scan_kernel(
    const int* __restrict__ counts, int* __restrict__ offsets,
    int* __restrict__ cursor) {
  __shared__ int sums[1024];
  const int t = threadIdx.x;
  int local[20];
  int base = t * 20;
  int s = 0;
#pragma unroll
  for (int c = 0; c < 20; ++c) {
    int idx = base + c;
    int v = (idx < NN) ? counts[idx] : 0;
    local[c] = s;
    s += v;
  }
  sums[t] = s;
  __syncthreads();
  for (int off = 1; off < 1024; off <<= 1) {
    int u = 0;
    if (t >= off) u = sums[t - off];
    __syncthreads();
    sums[t] += u;
    __syncthreads();
  }
  int prefix = sums[t] - s;  // exclusive over threads
#pragma unroll
  for (int c = 0; c < 20; ++c) {
    int idx = base + c;
    if (idx < NN) {
      int o = prefix + local[c];
      offsets[idx] = o;
      cursor[idx] = o;
    }
  }
  if (t == 0) offsets[NN] = NE;
}

__global__ __launch_bounds__(256) void scatter_kernel(
    const int* __restrict__ src, int* __restrict__ cursor,
    int* __restrict__ elist) {
  int e = blockIdx.x * 256 + threadIdx.x;
  if (e < NE) {
    int s = src[e];
    int pos = atomicAdd(&cursor[s], 1);
    elist[pos] = e;
  }
}

// ---------------- gather: per (node i, batch b) segment reduce --------------
__global__ __launch_bounds__(64) void gather_kernel(
    const unsigned short* __restrict__ hb, const float* __restrict__ g1,
    const float* __restrict__ g2, const int* __restrict__ dst,
    const int* __restrict__ offsets, const int* __restrict__ elist,
    float* __restrict__ out) {
  const int i = blockIdx.x;
  const int b = blockIdx.y;
  const int lane = threadIdx.x;
  const int beg = offsets[i];
  const int end = offsets[i + 1];
  const float g1i = g1[(size_t)b * NN + i];
  const float* g2b = g2 + (size_t)b * NN;
  const unsigned short* hbb = hb + (size_t)b * NN * 128;

  float accx = 0.f, accy = 0.f, rs = 0.f;
  // 2-deep software pipeline: dst 2 ahead, (g2, h-row) 1 ahead
  int dB = (beg + 1 < end) ? dst[elist[beg + 1]] : 0;
  int d0 = dst[elist[beg]];
  float gA = g2b[d0];
  ushort2 hA = *(const ushort2*)&hbb[(size_t)d0 * 128 + 2 * lane];
  for (int e = beg; e < end; ++e) {
    int dN = (e + 2 < end) ? dst[elist[e + 2]] : 0;
    float gB = 0.f;
    ushort2 hB = make_ushort2(0, 0);
    if (e + 1 < end) {
      gB = g2b[dB];
      hB = *(const ushort2*)&hbb[(size_t)dB * 128 + 2 * lane];
    }
    float s = g1i + gA;
    float sc = fmaxf(s, LRALPHA * s);   // leaky_relu
    float w = __expf(-sc);
    accx = fmaf(w, b2f(hA.x), accx);
    accy = fmaf(w, b2f(hA.y), accy);
    rs += w;
    gA = gB; hA = hB; dB = dN;
  }
  float inv = 1.f / rs;
  float ox = accx * inv, oy = accy * inv;
  ox = ox > 0.f ? ox : expm1f(ox);      // elu (alpha=1)
  oy = oy > 0.f ? oy : expm1f(oy);
  float2* op = (float2*)(out + ((size_t)b * NN + i) * 128);
  op[lane] = make_float2(ox, oy);
}

extern "C" void kernel_launch(void* const* d_in, const int* in_sizes, int n_in,
                              void* d_out, int out_size, void* d_ws, size_t ws_size,
                              hipStream_t stream) {
  const float* x = (const float*)d_in[0];
  const float* W = (const float*)d_in[1];
  const float* a = (const float*)d_in[2];
  const int* edge = (const int*)d_in[3];
  const int* src = edge;
  const int* dst = edge + NE;
  float* out = (float*)d_out;

  // workspace layout (~43.7 MB)
  char* p = (char*)d_ws;
  unsigned short* hb = (unsigned short*)p;  p += (size_t)ROWS * 128 * 2;  // 40.96 MB
  float* g1 = (float*)p;                    p += (size_t)ROWS * 4;
  float* g2 = (float*)p;                    p += (size_t)ROWS * 4;
  int* counts = (int*)p;                    p += (size_t)NN * 4;
  int* offsets = (int*)p;                   p += (size_t)(NN + 1) * 4;
  int* cursor = (int*)p;                    p += (size_t)NN * 4;
  int* elist = (int*)p;                     p += (size_t)NE * 4;

  hipMemsetAsync(counts, 0, NN * sizeof(int), stream);
  gemm_kernel<<<ROWS / 64, 256, 0, stream>>>(x, W, hb);
  g_kernel<<<ROWS / 4, 256, 0, stream>>>(hb, a, g1, g2);
  hist_kernel<<<(NE + 255) / 256, 256, 0, stream>>>(src, counts);
  scan_kernel<<<1, 1024, 0, stream>>>(counts, offsets, cursor);
  scatter_kernel<<<(NE + 255) / 256, 256, 0, stream>>>(src, cursor, elist);
  dim3 ggrid(NN, NB);
  gather_kernel<<<ggrid, 64, 0, stream>>>(hb, g1, g2, dst, offsets, elist, out);
}

// Round 2
// 301.319 us; speedup vs baseline: 1.4454x; 1.4454x over previous
//
#include <hip/hip_runtime.h>

#define NB 8
#define NN 20000
#define FI 128
#define FO 128
#define NE 320000
#define ROWS (NB * NN)        // 160000 flattened (b,n) rows
#define LRALPHA 0.2f

typedef short bf16x8 __attribute__((ext_vector_type(8)));
typedef float f32x4 __attribute__((ext_vector_type(4)));

static __device__ __forceinline__ float b2f(unsigned short u) {
  return __uint_as_float(((unsigned int)u) << 16);
}
static __device__ __forceinline__ unsigned short f2b(float f) {
  unsigned int u = __float_as_uint(f);
  return (unsigned short)((u + 0x7FFFu + ((u >> 16) & 1u)) >> 16);  // RNE
}

// ---- GEMM: h[row][o] = sum_k x[row][k]*W[k][o] (bf16 out) + fused g1/g2 ----
#define LDW 136  // padded LDS stride (bf16 elems): 2-way bank alias only (free)

__global__ __launch_bounds__(256) void gemm_kernel(
    const float* __restrict__ x, const float* __restrict__ W,
    const float* __restrict__ a,
    unsigned short* __restrict__ hb,
    float* __restrict__ g1, float* __restrict__ g2) {
  __shared__ __align__(16) unsigned short Wt[128 * LDW];  // Wt[n][k]  (transposed W)
  __shared__ __align__(16) unsigned short Xs[64 * LDW];   // Xs[r][k]
  const int tid = threadIdx.x;

  // stage W fp32 -> bf16, transposed
  for (int i = 0; i < 64; ++i) {
    int idx = tid + i * 256;        // 0..16383, coalesced read
    int k = idx >> 7, n = idx & 127;
    Wt[n * LDW + k] = f2b(W[idx]);
  }
  // stage 64 x-rows fp32 -> bf16
  const size_t row0 = (size_t)blockIdx.x * 64;
  const float4* xv = (const float4*)(x + row0 * 128);
  for (int i = 0; i < 8; ++i) {
    int c = tid + i * 256;          // float4 chunk 0..2047
    float4 v = xv[c];
    int r = c >> 5;                 // 32 float4 per 128-wide row
    int k = (c & 31) * 4;
    ushort4 o;
    o.x = f2b(v.x); o.y = f2b(v.y); o.z = f2b(v.z); o.w = f2b(v.w);
    *(ushort4*)&Xs[r * LDW + k] = o;
  }
  __syncthreads();

  const int wv = tid >> 6;          // wave 0..3 -> rows [wv*16, wv*16+16)
  const int lane = tid & 63;
  const int m = lane & 15;
  const int quad = lane >> 4;
  f32x4 acc[8] = {};
#pragma unroll
  for (int k0 = 0; k0 < 128; k0 += 32) {
    bf16x8 af = *(const bf16x8*)&Xs[(wv * 16 + m) * LDW + k0 + quad * 8];
#pragma unroll
    for (int c = 0; c < 8; ++c) {
      bf16x8 bf = *(const bf16x8*)&Wt[(c * 16 + m) * LDW + k0 + quad * 8];
      acc[c] = __builtin_amdgcn_mfma_f32_16x16x32_bf16(af, bf, acc[c], 0, 0, 0);
    }
  }
  // C/D layout: col = lane&15 (within c-tile), row = quad*4 + r
  unsigned short* hp = hb + (row0 + (size_t)wv * 16) * 128;
#pragma unroll
  for (int c = 0; c < 8; ++c)
#pragma unroll
    for (int r = 0; r < 4; ++r)
      hp[(quad * 4 + r) * 128 + c * 16 + m] = f2b(acc[c][r]);

  // fused g1/g2: per-row dot with a1/a2 from fp32 accumulators
  float a1v[8], a2v[8];
#pragma unroll
  for (int c = 0; c < 8; ++c) {
    a1v[c] = a[c * 16 + m];
    a2v[c] = a[128 + c * 16 + m];
  }
  float p1[4] = {}, p2[4] = {};
#pragma unroll
  for (int c = 0; c < 8; ++c)
#pragma unroll
    for (int r = 0; r < 4; ++r) {
      p1[r] = fmaf(acc[c][r], a1v[c], p1[r]);
      p2[r] = fmaf(acc[c][r], a2v[c], p2[r]);
    }
#pragma unroll
  for (int off = 1; off < 16; off <<= 1)
#pragma unroll
    for (int r = 0; r < 4; ++r) {
      p1[r] += __shfl_xor(p1[r], off, 64);
      p2[r] += __shfl_xor(p2[r], off, 64);
    }
  if (m == 0) {
    size_t rbase = row0 + wv * 16 + quad * 4;
#pragma unroll
    for (int r = 0; r < 4; ++r) {
      g1[rbase + r] = p1[r];
      g2[rbase + r] = p2[r];
    }
  }
}

// ---------------- CSR build: histogram -> scan -> scatter -------------------
__global__ __launch_bounds__(256) void hist_kernel(const int* __restrict__ src,
                                                   int* __restrict__ counts) {
  int e = blockIdx.x * 256 + threadIdx.x;
  if (e < NE) atomicAdd(&counts[src[e]], 1);
}

__global__ __launch_bounds__(1024) void scan_kernel(
    const int* __restrict__ counts, int* __restrict__ offsets,
    int* __restrict__ cursor) {
  __shared__ int sc[NN];      // 80 KB
  __shared__ int sums[1024];
  const int t = threadIdx.x;
  for (int idx = t; idx < NN; idx += 1024) sc[idx] = counts[idx];  // coalesced
  __syncthreads();
  int local[20];
  int base = t * 20;
  int s = 0;
#pragma unroll
  for (int c = 0; c < 20; ++c) {
    int idx = base + c;
    int v = (idx < NN) ? sc[idx] : 0;
    local[c] = s;
    s += v;
  }
  sums[t] = s;
  __syncthreads();
  for (int off = 1; off < 1024; off <<= 1) {
    int u = 0;
    if (t >= off) u = sums[t - off];
    __syncthreads();
    sums[t] += u;
    __syncthreads();
  }
  int prefix = sums[t] - s;  // exclusive over threads
#pragma unroll
  for (int c = 0; c < 20; ++c) {
    int idx = base + c;
    if (idx < NN) {
      int o = prefix + local[c];
      offsets[idx] = o;
      cursor[idx] = o;
    }
  }
  if (t == 0) offsets[NN] = NE;
}

__global__ __launch_bounds__(256) void scatter_kernel(
    const int* __restrict__ src, int* __restrict__ cursor,
    int* __restrict__ elist) {
  int e = blockIdx.x * 256 + threadIdx.x;
  if (e < NE) {
    int s = src[e];
    int pos = atomicAdd(&cursor[s], 1);
    elist[pos] = e;
  }
}

// ---------------- gather: per (node i, batch b) segment reduce --------------
// Lane-parallel weight compute + batched (8-deep) h-row load issuance.
__global__ __launch_bounds__(64) void gather_kernel(
    const unsigned short* __restrict__ hb, const float* __restrict__ g1,
    const float* __restrict__ g2, const int* __restrict__ dst,
    const int* __restrict__ offsets, const int* __restrict__ elist,
    float* __restrict__ out) {
  const int i = blockIdx.x;
  const int b = blockIdx.y;
  const int lane = threadIdx.x;
  const int beg = offsets[i];
  const int deg = offsets[i + 1] - beg;
  const float g1i = g1[(size_t)b * NN + i];
  const float* g2b = g2 + (size_t)b * NN;
  const unsigned short* hbb = hb + (size_t)b * NN * 128;

  float accx = 0.f, accy = 0.f, rs = 0.f;
  for (int c0 = 0; c0 < deg; c0 += 64) {
    const int cnt = min(64, deg - c0);
    // lane-parallel: lane e computes weight for edge beg+c0+e
    int myd = 0;
    float w = 0.f;
    if (lane < cnt) {
      int e = elist[beg + c0 + lane];
      myd = dst[e];
      float s = g1i + g2b[myd];
      float sc = fmaxf(s, LRALPHA * s);
      w = __expf(-sc);
    }
    rs += w;
    // accumulate h rows: broadcast (d,w) from lane j, 8 loads in flight
    const int cr = (cnt + 7) & ~7;  // zero-weight padding kills extras
    for (int e = 0; e < cr; e += 8) {
      ushort2 hv[8];
      float we[8];
#pragma unroll
      for (int j = 0; j < 8; ++j) {
        int d = __shfl(myd, e + j, 64);
        we[j] = __shfl(w, e + j, 64);
        hv[j] = *(const ushort2*)&hbb[(size_t)d * 128 + 2 * lane];
      }
#pragma unroll
      for (int j = 0; j < 8; ++j) {
        accx = fmaf(we[j], b2f(hv[j].x), accx);
        accy = fmaf(we[j], b2f(hv[j].y), accy);
      }
    }
  }
#pragma unroll
  for (int off = 32; off >= 1; off >>= 1) rs += __shfl_xor(rs, off, 64);
  float inv = 1.f / rs;
  float ox = accx * inv, oy = accy * inv;
  ox = ox > 0.f ? ox : expm1f(ox);      // elu (alpha=1)
  oy = oy > 0.f ? oy : expm1f(oy);
  float2* op = (float2*)(out + ((size_t)b * NN + i) * 128);
  op[lane] = make_float2(ox, oy);
}

extern "C" void kernel_launch(void* const* d_in, const int* in_sizes, int n_in,
                              void* d_out, int out_size, void* d_ws, size_t ws_size,
                              hipStream_t stream) {
  const float* x = (const float*)d_in[0];
  const float* W = (const float*)d_in[1];
  const float* a = (const float*)d_in[2];
  const int* edge = (const int*)d_in[3];
  const int* src = edge;
  const int* dst = edge + NE;
  float* out = (float*)d_out;

  // workspace layout (~43.7 MB)
  char* p = (char*)d_ws;
  unsigned short* hb = (unsigned short*)p;  p += (size_t)ROWS * 128 * 2;  // 40.96 MB
  float* g1 = (float*)p;                    p += (size_t)ROWS * 4;
  float* g2 = (float*)p;                    p += (size_t)ROWS * 4;
  int* counts = (int*)p;                    p += (size_t)NN * 4;
  int* offsets = (int*)p;                   p += (size_t)(NN + 1) * 4;
  int* cursor = (int*)p;                    p += (size_t)NN * 4;
  int* elist = (int*)p;                     p += (size_t)NE * 4;

  hipMemsetAsync(counts, 0, NN * sizeof(int), stream);
  gemm_kernel<<<ROWS / 64, 256, 0, stream>>>(x, W, a, hb, g1, g2);
  hist_kernel<<<(NE + 255) / 256, 256, 0, stream>>>(src, counts);
  scan_kernel<<<1, 1024, 0, stream>>>(counts, offsets, cursor);
  scatter_kernel<<<(NE + 255) / 256, 256, 0, stream>>>(src, cursor, elist);
  dim3 ggrid(NN, NB);
  gather_kernel<<<ggrid, 64, 0, stream>>>(hb, g1, g2, dst, offsets, elist, out);
}